// Round 1
// baseline (658.573 us; speedup 1.0000x reference)
//
#include <hip/hip_runtime.h>
#include <math.h>

#define VOCABN 100
#define EMBEDN 50
#define HID 30
#define NB 512
#define NT 512
#define G4 120  // 4*HID

__device__ __forceinline__ float sigm(float x) { return 1.0f / (1.0f + __expf(-x)); }
__device__ __forceinline__ float tanh_f(float x) { return 1.0f - 2.0f / (1.0f + __expf(2.0f * x)); }

// ---------------- prep: xpe[tok][g] = emb[tok] @ w_ih1^T + b_ih1 + b_hh1 ; b2s = b_ih2+b_hh2
__global__ void prep_kernel(const float* __restrict__ emb,
                            const float* __restrict__ w_ih1,
                            const float* __restrict__ b_ih1,
                            const float* __restrict__ b_hh1,
                            const float* __restrict__ b_ih2,
                            const float* __restrict__ b_hh2,
                            float* __restrict__ xpe, float* __restrict__ b2s) {
  __shared__ float e[EMBEDN];
  int r = blockIdx.x;
  int tid = threadIdx.x;
  if (tid < EMBEDN) e[tid] = emb[r * EMBEDN + tid];
  __syncthreads();
  if (tid < G4) {
    float s = b_ih1[tid] + b_hh1[tid];
#pragma unroll
    for (int k = 0; k < EMBEDN; ++k) s = fmaf(e[k], w_ih1[tid * EMBEDN + k], s);
    xpe[r * G4 + tid] = s;
    if (r == 0) b2s[tid] = b_ih2[tid] + b_hh2[tid];
  }
}

// ---------------- scan: one wave per batch row, both LSTM layers fused, early exit at len[b]
__global__ void __launch_bounds__(64) scan_kernel(
    const int* __restrict__ batch_x, const int* __restrict__ lens,
    const float* __restrict__ xpe, const float* __restrict__ b2s,
    const float* __restrict__ w_hh1, const float* __restrict__ w_ih2,
    const float* __restrict__ w_hh2, float* __restrict__ h2g) {
  __shared__ __align__(16) float h1_lds[32];
  __shared__ __align__(16) float h2_lds[32];
  int b = blockIdx.x;
  int lane = threadIdx.x;
  int half = lane >> 5;
  int j = lane & 31;
  int jj = (j < HID) ? j : (HID - 1);
  // half0 lane j: gates (i_j, f_j) ; half1 lane j: gates (g_j, o_j)
  int gA = half ? (jj + 2 * HID) : jj;
  int gB = half ? (jj + 3 * HID) : (jj + HID);

  float w1A[32], w1B[32], wi2A[32], wi2B[32], wh2A[32], wh2B[32];
#pragma unroll
  for (int k = 0; k < 32; ++k) {
    w1A[k] = 0.f; w1B[k] = 0.f; wi2A[k] = 0.f;
    wi2B[k] = 0.f; wh2A[k] = 0.f; wh2B[k] = 0.f;
  }
#pragma unroll
  for (int k = 0; k < HID; ++k) {
    w1A[k] = w_hh1[gA * HID + k];
    w1B[k] = w_hh1[gB * HID + k];
    wi2A[k] = w_ih2[gA * HID + k];
    wi2B[k] = w_ih2[gB * HID + k];
    wh2A[k] = w_hh2[gA * HID + k];
    wh2B[k] = w_hh2[gB * HID + k];
  }
  float b2A = b2s[gA], b2B = b2s[gB];
  if (lane < 32) { h1_lds[lane] = 0.f; h2_lds[lane] = 0.f; }
  float c1 = 0.f, c2 = 0.f;
  int len = lens[b];
  const int* xrow = batch_x + b * NT;
  __syncthreads();

  const float4* h1v = reinterpret_cast<const float4*>(h1_lds);
  const float4* h2v = reinterpret_cast<const float4*>(h2_lds);

  for (int t = 0; t < len; ++t) {
    int tok = xrow[t];
    const float* xr = xpe + tok * G4;
    float xa = xr[gA], xb = xr[gB];
    // ---- layer 1 gates: dot(h1_prev, w_hh1 rows) + xpe
    float a0 = 0.f, a1 = 0.f;
#pragma unroll
    for (int q = 0; q < 8; ++q) {
      float4 hv = h1v[q];
      a0 = fmaf(hv.x, w1A[4 * q + 0], a0); a1 = fmaf(hv.x, w1B[4 * q + 0], a1);
      a0 = fmaf(hv.y, w1A[4 * q + 1], a0); a1 = fmaf(hv.y, w1B[4 * q + 1], a1);
      a0 = fmaf(hv.z, w1A[4 * q + 2], a0); a1 = fmaf(hv.z, w1B[4 * q + 2], a1);
      a0 = fmaf(hv.w, w1A[4 * q + 3], a0); a1 = fmaf(hv.w, w1B[4 * q + 3], a1);
    }
    a0 += xa; a1 += xb;
    float sA = half ? tanh_f(a0) : sigm(a0);
    float sB = sigm(a1);
    float tA = __shfl_xor(sA, 32, 64);
    float tB = __shfl_xor(sB, 32, 64);
    float i_ = half ? tA : sA;
    float f_ = half ? tB : sB;
    float g_ = half ? sA : tA;
    float o_ = half ? sB : tB;
    c1 = fmaf(f_, c1, i_ * g_);
    float h1n = o_ * tanh_f(c1);
    __syncthreads();                       // everyone done reading h1_lds (prev)
    if (lane < HID) h1_lds[lane] = h1n;
    __syncthreads();                       // h1_lds (new) visible
    // ---- layer 2 gates: dot(h1_new, w_ih2) + dot(h2_prev, w_hh2) + b2s
    float p0 = 0.f, p1 = 0.f, r0 = 0.f, r1 = 0.f;
#pragma unroll
    for (int q = 0; q < 8; ++q) {
      float4 hv = h1v[q];
      float4 gv = h2v[q];
      p0 = fmaf(hv.x, wi2A[4 * q + 0], p0); p1 = fmaf(hv.x, wi2B[4 * q + 0], p1);
      r0 = fmaf(gv.x, wh2A[4 * q + 0], r0); r1 = fmaf(gv.x, wh2B[4 * q + 0], r1);
      p0 = fmaf(hv.y, wi2A[4 * q + 1], p0); p1 = fmaf(hv.y, wi2B[4 * q + 1], p1);
      r0 = fmaf(gv.y, wh2A[4 * q + 1], r0); r1 = fmaf(gv.y, wh2B[4 * q + 1], r1);
      p0 = fmaf(hv.z, wi2A[4 * q + 2], p0); p1 = fmaf(hv.z, wi2B[4 * q + 2], p1);
      r0 = fmaf(gv.z, wh2A[4 * q + 2], r0); r1 = fmaf(gv.z, wh2B[4 * q + 2], r1);
      p0 = fmaf(hv.w, wi2A[4 * q + 3], p0); p1 = fmaf(hv.w, wi2B[4 * q + 3], p1);
      r0 = fmaf(gv.w, wh2A[4 * q + 3], r0); r1 = fmaf(gv.w, wh2B[4 * q + 3], r1);
    }
    float a20 = p0 + r0 + b2A;
    float a21 = p1 + r1 + b2B;
    sA = half ? tanh_f(a20) : sigm(a20);
    sB = sigm(a21);
    tA = __shfl_xor(sA, 32, 64);
    tB = __shfl_xor(sB, 32, 64);
    i_ = half ? tA : sA;
    f_ = half ? tB : sB;
    g_ = half ? sA : tA;
    o_ = half ? sB : tB;
    c2 = fmaf(f_, c2, i_ * g_);
    float h2n = o_ * tanh_f(c2);
    __syncthreads();                       // everyone done reading h2_lds (prev)
    if (lane < HID) {
      h2_lds[lane] = h2n;
      h2g[(size_t)(t * NB + b) * HID + lane] = h2n;
    }
    __syncthreads();
  }
}

// ---------------- head MLP: out = relu(h2*lw1^T+lb1)*lw2^T+lb2, zeros for masked t
#define ROWS_PER_BLOCK 32
__global__ void __launch_bounds__(128) final_kernel(
    const float* __restrict__ h2g, const int* __restrict__ lens,
    const float* __restrict__ lw1, const float* __restrict__ lb1,
    const float* __restrict__ lw2, const float* __restrict__ lb2,
    float* __restrict__ out) {
  __shared__ float lw1s[HID][33];
  __shared__ float lw2s[VOCABN][33];
  __shared__ float lb1s[HID];
  __shared__ float lb2s[VOCABN];
  __shared__ float hrow[4][32];
  __shared__ float hmid[4][32];
  int tid = threadIdx.x;
  for (int idx = tid; idx < HID * HID; idx += 128) lw1s[idx / HID][idx % HID] = lw1[idx];
  for (int idx = tid; idx < VOCABN * HID; idx += 128) lw2s[idx / HID][idx % HID] = lw2[idx];
  if (tid < HID) lb1s[tid] = lb1[tid];
  if (tid < VOCABN) lb2s[tid] = lb2[tid];
  __syncthreads();
  int row0 = blockIdx.x * ROWS_PER_BLOCK;
  for (int it = 0; it < ROWS_PER_BLOCK / 4; ++it) {
    int rbase = row0 + it * 4;
    if (tid < 4 * HID) {
      int rid = tid / HID, k = tid % HID;
      int row = rbase + rid;
      int b = row >> 9;        // row / NT
      int t = row & (NT - 1);  // row % NT
      float v = 0.f;
      if (t < lens[b]) v = h2g[(size_t)(t * NB + b) * HID + k];
      hrow[rid][k] = v;
    }
    __syncthreads();
    {
      int rid = tid >> 5, rl = tid & 31;
      if (rl < HID) {
        float m = lb1s[rl];
#pragma unroll
        for (int k = 0; k < HID; ++k) m = fmaf(hrow[rid][k], lw1s[rl][k], m);
        hmid[rid][rl] = fmaxf(m, 0.f);
      }
    }
    __syncthreads();
#pragma unroll
    for (int s = 0; s < 4; ++s) {
      int e = tid + 128 * s;
      if (e < 4 * VOCABN) {
        int rid = e / VOCABN, v = e % VOCABN;
        float o = lb2s[v];
#pragma unroll
        for (int k = 0; k < HID; ++k) o = fmaf(hmid[rid][k], lw2s[v][k], o);
        out[(size_t)(rbase + rid) * VOCABN + v] = o;
      }
    }
    __syncthreads();
  }
}

extern "C" void kernel_launch(void* const* d_in, const int* in_sizes, int n_in,
                              void* d_out, int out_size, void* d_ws, size_t ws_size,
                              hipStream_t stream) {
  const int* batch_x = (const int*)d_in[0];
  const int* lens = (const int*)d_in[1];
  const float* emb = (const float*)d_in[2];
  const float* w_ih1 = (const float*)d_in[3];
  const float* w_hh1 = (const float*)d_in[4];
  const float* b_ih1 = (const float*)d_in[5];
  const float* b_hh1 = (const float*)d_in[6];
  const float* w_ih2 = (const float*)d_in[7];
  const float* w_hh2 = (const float*)d_in[8];
  const float* b_ih2 = (const float*)d_in[9];
  const float* b_hh2 = (const float*)d_in[10];
  const float* lw1 = (const float*)d_in[11];
  const float* lb1 = (const float*)d_in[12];
  const float* lw2 = (const float*)d_in[13];
  const float* lb2 = (const float*)d_in[14];
  float* out = (float*)d_out;

  char* ws = (char*)d_ws;
  float* xpe = (float*)ws;                  // 100*120 floats
  float* b2s = (float*)(ws + 48 * 1024);    // 120 floats
  float* h2g = (float*)(ws + 64 * 1024);    // 512*512*30 floats (~31.5 MB)

  prep_kernel<<<VOCABN, 128, 0, stream>>>(emb, w_ih1, b_ih1, b_hh1, b_ih2, b_hh2, xpe, b2s);
  scan_kernel<<<NB, 64, 0, stream>>>(batch_x, lens, xpe, b2s, w_hh1, w_ih2, w_hh2, h2g);
  final_kernel<<<(NB * NT) / ROWS_PER_BLOCK, 128, 0, stream>>>(h2g, lens, lw1, lb1, lw2, lb2, out);
}

// Round 2
// 470.859 us; speedup vs baseline: 1.3987x; 1.3987x over previous
//
#include <hip/hip_runtime.h>
#include <math.h>

#define VOCABN 100
#define EMBEDN 50
#define HID 30
#define NB 512
#define NT 512
#define G4 120  // 4*HID

typedef float v2f __attribute__((ext_vector_type(2)));

__device__ __forceinline__ float tanh_f(float x) { return 1.0f - 2.0f / (1.0f + __expf(2.0f * x)); }
__device__ __forceinline__ v2f mk2(float a, float b) { v2f r; r[0] = a; r[1] = b; return r; }

// ---------------- prep: xpe[tok][g] = emb[tok] @ w_ih1^T + b_ih1 + b_hh1 ; b2s = b_ih2+b_hh2
__global__ void prep_kernel(const float* __restrict__ emb,
                            const float* __restrict__ w_ih1,
                            const float* __restrict__ b_ih1,
                            const float* __restrict__ b_hh1,
                            const float* __restrict__ b_ih2,
                            const float* __restrict__ b_hh2,
                            float* __restrict__ xpe, float* __restrict__ b2s) {
  __shared__ float e[EMBEDN];
  int r = blockIdx.x;
  int tid = threadIdx.x;
  if (tid < EMBEDN) e[tid] = emb[r * EMBEDN + tid];
  __syncthreads();
  if (tid < G4) {
    float s = b_ih1[tid] + b_hh1[tid];
#pragma unroll
    for (int k = 0; k < EMBEDN; ++k) s = fmaf(e[k], w_ih1[tid * EMBEDN + k], s);
    xpe[r * G4 + tid] = s;
    if (r == 0) b2s[tid] = b_ih2[tid] + b_hh2[tid];
  }
}

// ---------------- scan: one wave per batch row, barrier-free, software-pipelined.
// Per iteration t: computes layer2[t] (from h1[t], h2[t-1]) AND layer1[t+1] (from h1[t],
// prefetched xpe) — independent chains, interleaved by the scheduler.
__global__ void __launch_bounds__(64, 1) scan_kernel(
    const int* __restrict__ batch_x, const int* __restrict__ lens,
    const float* __restrict__ xpe, const float* __restrict__ b2s,
    const float* __restrict__ w_hh1, const float* __restrict__ w_ih2,
    const float* __restrict__ w_hh2, float* __restrict__ h2g) {
  __shared__ __align__(16) float h1_lds[32];
  __shared__ __align__(16) float h2_lds[32];
  __shared__ int tok_lds[NT];
  const int b = blockIdx.x;
  const int lane = threadIdx.x;
  const int half = lane >> 5;
  const int j = lane & 31;
  const int jj = (j < HID) ? j : (HID - 1);
  // half0 lane j: gates (i_j, f_j) ; half1 lane j: gates (g_j, o_j)
  const int gA = half ? (jj + 2 * HID) : jj;
  const int gB = half ? (jj + 3 * HID) : (jj + HID);
  const float bg = half ? 2.0f : 1.0f;  // beta=gamma: 1 -> sigmoid, 2 -> tanh

  const int* xrow = batch_x + b * NT;
#pragma unroll
  for (int i = 0; i < NT / 64; ++i) tok_lds[lane + (i << 6)] = xrow[lane + (i << 6)];

  // weight rows, register-resident as float2 pairs (launch_bounds(64,1) permits ~300 VGPRs)
  v2f w1A[15], w1B[15], wiA[15], wiB[15], whA[15], whB[15];
  {
    const float* rA1 = w_hh1 + gA * HID;
    const float* rB1 = w_hh1 + gB * HID;
    const float* rAi = w_ih2 + gA * HID;
    const float* rBi = w_ih2 + gB * HID;
    const float* rAh = w_hh2 + gA * HID;
    const float* rBh = w_hh2 + gB * HID;
#pragma unroll
    for (int p = 0; p < 15; ++p) {
      w1A[p] = mk2(rA1[2 * p], rA1[2 * p + 1]);
      w1B[p] = mk2(rB1[2 * p], rB1[2 * p + 1]);
      wiA[p] = mk2(rAi[2 * p], rAi[2 * p + 1]);
      wiB[p] = mk2(rBi[2 * p], rBi[2 * p + 1]);
      whA[p] = mk2(rAh[2 * p], rAh[2 * p + 1]);
      whB[p] = mk2(rBh[2 * p], rBh[2 * p + 1]);
    }
  }
  const float b2A = b2s[gA], b2B = b2s[gB];
  const int len = lens[b];

  if (lane < 32) h2_lds[j] = 0.0f;
  float c1 = 0.0f, c2 = 0.0f;

  // ---- prologue: h1[0] = LSTM1(x[0], 0)
  {
    int tok0 = tok_lds[0];
    float a0 = xpe[tok0 * G4 + gA];
    float a1 = xpe[tok0 * G4 + gB];
    float sA = 1.0f - bg / (1.0f + __expf(bg * a0));
    float sB = 1.0f - 1.0f / (1.0f + __expf(a1));
    float tA = __shfl_xor(sA, 32, 64);
    float tB = __shfl_xor(sB, 32, 64);
    float i_ = half ? tA : sA, f_ = half ? tB : sB;
    float g_ = half ? sA : tA, o_ = half ? sB : tB;
    (void)f_;
    c1 = i_ * g_;  // f * c_prev(=0) + i*g
    float h1n = o_ * tanh_f(c1);
    if (lane < 32) h1_lds[j] = h1n;
  }

  v2f h1r[15], h2r[15];
  const v2f* h1p = (const v2f*)h1_lds;
  const v2f* h2p = (const v2f*)h2_lds;
#pragma unroll
  for (int p = 0; p < 15; ++p) { h1r[p] = h1p[p]; h2r[p] = h2p[p]; }

  // xpe values for t=1 (consumed by layer1 inside iter t=0)
  int tk1 = tok_lds[1];
  float xaC = xpe[tk1 * G4 + gA];
  float xbC = xpe[tk1 * G4 + gB];

  for (int t = 0; t < len; ++t) {
    // prefetch xpe for t+2 (tokens known; 1.5 iterations of slack)
    int t2 = t + 2;
    t2 = t2 < NT ? t2 : NT - 1;
    int tk = tok_lds[t2];
    float xaN = xpe[tk * G4 + gA];
    float xbN = xpe[tk * G4 + gB];

    v2f accA = mk2(0.f, 0.f), accB = mk2(0.f, 0.f);  // layer1[t+1] h-dot
    v2f pA = mk2(0.f, 0.f), pB = mk2(0.f, 0.f);      // layer2[t] h1-dot
    v2f rA = mk2(0.f, 0.f), rB = mk2(0.f, 0.f);      // layer2[t] h2-dot
#pragma unroll
    for (int p = 0; p < 15; ++p) {
      accA = __builtin_elementwise_fma(h1r[p], w1A[p], accA);
      accB = __builtin_elementwise_fma(h1r[p], w1B[p], accB);
      pA = __builtin_elementwise_fma(h1r[p], wiA[p], pA);
      pB = __builtin_elementwise_fma(h1r[p], wiB[p], pB);
      rA = __builtin_elementwise_fma(h2r[p], whA[p], rA);
      rB = __builtin_elementwise_fma(h2r[p], whB[p], rB);
    }
    float a0 = accA[0] + accA[1] + xaC;
    float a1 = accB[0] + accB[1] + xbC;
    float q0 = pA[0] + pA[1] + rA[0] + rA[1] + b2A;
    float q1 = pB[0] + pB[1] + rB[0] + rB[1] + b2B;

    // branchless nonlinearities: s(x) = 1 - beta/(1 + exp(beta*x))
    float sA = 1.0f - bg / (1.0f + __expf(bg * a0));   // layer1
    float sB = 1.0f - 1.0f / (1.0f + __expf(a1));
    float uA = 1.0f - bg / (1.0f + __expf(bg * q0));   // layer2
    float uB = 1.0f - 1.0f / (1.0f + __expf(q1));
    float tA = __shfl_xor(sA, 32, 64);
    float tB = __shfl_xor(sB, 32, 64);
    float vA = __shfl_xor(uA, 32, 64);
    float vB = __shfl_xor(uB, 32, 64);

    float i1 = half ? tA : sA, f1 = half ? tB : sB;
    float g1 = half ? sA : tA, o1 = half ? sB : tB;
    c1 = fmaf(f1, c1, i1 * g1);
    float h1n = o1 * tanh_f(c1);  // h1[t+1]

    float i2 = half ? vA : uA, f2 = half ? vB : uB;
    float g2 = half ? uA : vA, o2 = half ? uB : vB;
    c2 = fmaf(f2, c2, i2 * g2);
    float h2n = o2 * tanh_f(c2);  // h2[t]

    if (lane < HID) h2g[((size_t)t * NB + b) * HID + lane] = h2n;
    if (lane < 32) {
      h1_lds[j] = h1n;  // lanes 30,31 write ch29 dup into pad slots — never read
      h2_lds[j] = h2n;
    }
    // re-read immediately; ~120cyc LDS latency hides under next iter's dot block
#pragma unroll
    for (int p = 0; p < 15; ++p) { h1r[p] = h1p[p]; h2r[p] = h2p[p]; }
    xaC = xaN;
    xbC = xbN;
  }
}

// ---------------- head MLP: out = relu(h2*lw1^T+lb1)*lw2^T+lb2, zeros for masked t
#define ROWS_PER_BLOCK 32
__global__ void __launch_bounds__(128) final_kernel(
    const float* __restrict__ h2g, const int* __restrict__ lens,
    const float* __restrict__ lw1, const float* __restrict__ lb1,
    const float* __restrict__ lw2, const float* __restrict__ lb2,
    float* __restrict__ out) {
  __shared__ float lw1s[HID][33];
  __shared__ float lw2s[VOCABN][33];
  __shared__ float lb1s[HID];
  __shared__ float lb2s[VOCABN];
  __shared__ float hrow[4][32];
  __shared__ float hmid[4][32];
  int tid = threadIdx.x;
  for (int idx = tid; idx < HID * HID; idx += 128) lw1s[idx / HID][idx % HID] = lw1[idx];
  for (int idx = tid; idx < VOCABN * HID; idx += 128) lw2s[idx / HID][idx % HID] = lw2[idx];
  if (tid < HID) lb1s[tid] = lb1[tid];
  if (tid < VOCABN) lb2s[tid] = lb2[tid];
  __syncthreads();
  int row0 = blockIdx.x * ROWS_PER_BLOCK;
  for (int it = 0; it < ROWS_PER_BLOCK / 4; ++it) {
    int rbase = row0 + it * 4;
    if (tid < 4 * HID) {
      int rid = tid / HID, k = tid % HID;
      int row = rbase + rid;
      int b = row >> 9;        // row / NT
      int t = row & (NT - 1);  // row % NT
      float v = 0.f;
      if (t < lens[b]) v = h2g[(size_t)(t * NB + b) * HID + k];
      hrow[rid][k] = v;
    }
    __syncthreads();
    {
      int rid = tid >> 5, rl = tid & 31;
      if (rl < HID) {
        float m = lb1s[rl];
#pragma unroll
        for (int k = 0; k < HID; ++k) m = fmaf(hrow[rid][k], lw1s[rl][k], m);
        hmid[rid][rl] = fmaxf(m, 0.f);
      }
    }
    __syncthreads();
#pragma unroll
    for (int s = 0; s < 4; ++s) {
      int e = tid + 128 * s;
      if (e < 4 * VOCABN) {
        int rid = e / VOCABN, v = e % VOCABN;
        float o = lb2s[v];
#pragma unroll
        for (int k = 0; k < HID; ++k) o = fmaf(hmid[rid][k], lw2s[v][k], o);
        out[(size_t)(rbase + rid) * VOCABN + v] = o;
      }
    }
    __syncthreads();
  }
}

extern "C" void kernel_launch(void* const* d_in, const int* in_sizes, int n_in,
                              void* d_out, int out_size, void* d_ws, size_t ws_size,
                              hipStream_t stream) {
  const int* batch_x = (const int*)d_in[0];
  const int* lens = (const int*)d_in[1];
  const float* emb = (const float*)d_in[2];
  const float* w_ih1 = (const float*)d_in[3];
  const float* w_hh1 = (const float*)d_in[4];
  const float* b_ih1 = (const float*)d_in[5];
  const float* b_hh1 = (const float*)d_in[6];
  const float* w_ih2 = (const float*)d_in[7];
  const float* w_hh2 = (const float*)d_in[8];
  const float* b_ih2 = (const float*)d_in[9];
  const float* b_hh2 = (const float*)d_in[10];
  const float* lw1 = (const float*)d_in[11];
  const float* lb1 = (const float*)d_in[12];
  const float* lw2 = (const float*)d_in[13];
  const float* lb2 = (const float*)d_in[14];
  float* out = (float*)d_out;

  char* ws = (char*)d_ws;
  float* xpe = (float*)ws;                // 100*120 floats
  float* b2s = (float*)(ws + 48 * 1024);  // 120 floats
  float* h2g = (float*)(ws + 64 * 1024);  // 512*512*30 floats (~31.5 MB)

  prep_kernel<<<VOCABN, 128, 0, stream>>>(emb, w_ih1, b_ih1, b_hh1, b_ih2, b_hh2, xpe, b2s);
  scan_kernel<<<NB, 64, 0, stream>>>(batch_x, lens, xpe, b2s, w_hh1, w_ih2, w_hh2, h2g);
  final_kernel<<<(NB * NT) / ROWS_PER_BLOCK, 128, 0, stream>>>(h2g, lens, lw1, lb1, lw2, lb2, out);
}

// Round 3
// 461.006 us; speedup vs baseline: 1.4286x; 1.0214x over previous
//
#include <hip/hip_runtime.h>
#include <math.h>

#define VOCABN 100
#define EMBEDN 50
#define HID 30
#define NB 512
#define NT 512
#define G4 120  // 4*HID

typedef float v2f __attribute__((ext_vector_type(2)));

__device__ __forceinline__ float tanh_f(float x) { return 1.0f - 2.0f / (1.0f + __expf(2.0f * x)); }
__device__ __forceinline__ v2f mk2(float a, float b) { v2f r; r[0] = a; r[1] = b; return r; }

// ---------------- prep: xpe[tok][g] = emb[tok] @ w_ih1^T + b_ih1 + b_hh1 ; b2s = b_ih2+b_hh2
__global__ void prep_kernel(const float* __restrict__ emb,
                            const float* __restrict__ w_ih1,
                            const float* __restrict__ b_ih1,
                            const float* __restrict__ b_hh1,
                            const float* __restrict__ b_ih2,
                            const float* __restrict__ b_hh2,
                            float* __restrict__ xpe, float* __restrict__ b2s) {
  __shared__ float e[EMBEDN];
  int r = blockIdx.x;
  int tid = threadIdx.x;
  if (tid < EMBEDN) e[tid] = emb[r * EMBEDN + tid];
  __syncthreads();
  if (tid < G4) {
    float s = b_ih1[tid] + b_hh1[tid];
#pragma unroll
    for (int k = 0; k < EMBEDN; ++k) s = fmaf(e[k], w_ih1[tid * EMBEDN + k], s);
    xpe[r * G4 + tid] = s;
    if (r == 0) b2s[tid] = b_ih2[tid] + b_hh2[tid];
  }
}

// ---------------- scan: one wave per batch row, barrier-free, software-pipelined.
// xpe table fully LDS-resident -> zero global LOADS in the t-loop (only the h2g store,
// so no vmcnt waits ever block the chain). Weights register-resident via waves_per_eu(1,1).
__global__ void __launch_bounds__(64)
__attribute__((amdgpu_waves_per_eu(1, 1)))
scan_kernel(const int* __restrict__ batch_x, const int* __restrict__ lens,
            const float* __restrict__ xpe, const float* __restrict__ b2s,
            const float* __restrict__ w_hh1, const float* __restrict__ w_ih2,
            const float* __restrict__ w_hh2, float* __restrict__ h2g) {
  __shared__ __align__(16) float xpl[VOCABN * G4];  // 46.9 KB
  __shared__ int tok_lds[NT];                       // 2 KB
  __shared__ __align__(16) float h1_lds[32];
  __shared__ __align__(16) float h2_lds[32];
  const int b = blockIdx.x;
  const int lane = threadIdx.x;
  const int half = lane >> 5;
  const int j = lane & 31;
  const int jj = (j < HID) ? j : (HID - 1);
  // half0 lane j: gates (i_j, f_j) ; half1 lane j: gates (g_j, o_j)
  const int gA = half ? (jj + 2 * HID) : jj;
  const int gB = half ? (jj + 3 * HID) : (jj + HID);
  const float bg = half ? 2.0f : 1.0f;  // beta: 1 -> sigmoid, 2 -> tanh

  // ---- stage tokens + xpe table into LDS (single wave: no barriers needed)
  const int* xrow = batch_x + b * NT;
#pragma unroll
  for (int i = 0; i < NT / 64; ++i) tok_lds[lane + (i << 6)] = xrow[lane + (i << 6)];
  {
    const float4* src = (const float4*)xpe;
    float4* dst = (float4*)xpl;
#pragma unroll
    for (int i = 0; i < (VOCABN * G4) / 4 / 64 + 1; ++i) {
      int idx = lane + (i << 6);
      if (idx < (VOCABN * G4) / 4) dst[idx] = src[idx];
    }
  }

  // ---- weight rows, register-resident as float2 pairs
  v2f w1A[15], w1B[15], wiA[15], wiB[15], whA[15], whB[15];
  {
    const float* rA1 = w_hh1 + gA * HID;
    const float* rB1 = w_hh1 + gB * HID;
    const float* rAi = w_ih2 + gA * HID;
    const float* rBi = w_ih2 + gB * HID;
    const float* rAh = w_hh2 + gA * HID;
    const float* rBh = w_hh2 + gB * HID;
#pragma unroll
    for (int p = 0; p < 15; ++p) {
      w1A[p] = mk2(rA1[2 * p], rA1[2 * p + 1]);
      w1B[p] = mk2(rB1[2 * p], rB1[2 * p + 1]);
      wiA[p] = mk2(rAi[2 * p], rAi[2 * p + 1]);
      wiB[p] = mk2(rBi[2 * p], rBi[2 * p + 1]);
      whA[p] = mk2(rAh[2 * p], rAh[2 * p + 1]);
      whB[p] = mk2(rBh[2 * p], rBh[2 * p + 1]);
    }
  }
  const float b2A = b2s[gA], b2B = b2s[gB];
  const int len = lens[b];

  if (lane < 32) h2_lds[j] = 0.0f;
  float c1 = 0.0f, c2 = 0.0f;

  // ---- prologue: h1[0] = LSTM1(x[0], 0)
  {
    int tok0 = tok_lds[0];
    float a0 = xpl[tok0 * G4 + gA];
    float a1 = xpl[tok0 * G4 + gB];
    float sA = 1.0f - bg / (1.0f + __expf(bg * a0));
    float sB = 1.0f - 1.0f / (1.0f + __expf(a1));
    float tA = __shfl_xor(sA, 32, 64);
    float tB = __shfl_xor(sB, 32, 64);
    float i_ = half ? tA : sA;
    float g_ = half ? sA : tA, o_ = half ? sB : tB;
    c1 = i_ * g_;  // f*c_prev(=0) + i*g
    float h1n = o_ * tanh_f(c1);
    if (lane < 32) h1_lds[j] = h1n;
    (void)tB;
  }

  v2f h1r[15], h2r[15];
  const v2f* h1p = (const v2f*)h1_lds;
  const v2f* h2p = (const v2f*)h2_lds;
#pragma unroll
  for (int p = 0; p < 15; ++p) { h1r[p] = h1p[p]; h2r[p] = h2p[p]; }

#pragma unroll 2
  for (int t = 0; t < len; ++t) {
    // xpe for t+1 (consumed by layer1[t+1] at bottom of this iteration); LDS, ~120cyc,
    // issued here so it hides under the dot block.
    int tp = t + 1;
    tp = tp < NT ? tp : NT - 1;
    int tk = tok_lds[tp];
    float xaC = xpl[tk * G4 + gA];
    float xbC = xpl[tk * G4 + gB];

    v2f accA = mk2(0.f, 0.f), accB = mk2(0.f, 0.f);  // layer1[t+1] h-dot
    v2f pA = mk2(0.f, 0.f), pB = mk2(0.f, 0.f);      // layer2[t] h1-dot
    v2f rA = mk2(0.f, 0.f), rB = mk2(0.f, 0.f);      // layer2[t] h2-dot
#pragma unroll
    for (int p = 0; p < 15; ++p) {
      accA = __builtin_elementwise_fma(h1r[p], w1A[p], accA);
      accB = __builtin_elementwise_fma(h1r[p], w1B[p], accB);
      pA = __builtin_elementwise_fma(h1r[p], wiA[p], pA);
      pB = __builtin_elementwise_fma(h1r[p], wiB[p], pB);
      rA = __builtin_elementwise_fma(h2r[p], whA[p], rA);
      rB = __builtin_elementwise_fma(h2r[p], whB[p], rB);
    }
    float a0 = accA[0] + accA[1] + xaC;
    float a1 = accB[0] + accB[1] + xbC;
    float q0 = pA[0] + pA[1] + rA[0] + rA[1] + b2A;
    float q1 = pB[0] + pB[1] + rB[0] + rB[1] + b2B;

    // branchless nonlinearities: s(x) = 1 - beta/(1 + exp(beta*x))
    float sA = 1.0f - bg / (1.0f + __expf(bg * a0));  // layer1
    float sB = 1.0f - 1.0f / (1.0f + __expf(a1));
    float uA = 1.0f - bg / (1.0f + __expf(bg * q0));  // layer2
    float uB = 1.0f - 1.0f / (1.0f + __expf(q1));
    float tA = __shfl_xor(sA, 32, 64);
    float tB = __shfl_xor(sB, 32, 64);
    float vA = __shfl_xor(uA, 32, 64);
    float vB = __shfl_xor(uB, 32, 64);

    float i1 = half ? tA : sA, f1 = half ? tB : sB;
    float g1 = half ? sA : tA, o1 = half ? sB : tB;
    c1 = fmaf(f1, c1, i1 * g1);
    float h1n = o1 * tanh_f(c1);  // h1[t+1]

    float i2 = half ? vA : uA, f2 = half ? vB : uB;
    float g2 = half ? uA : vA, o2 = half ? uB : vB;
    c2 = fmaf(f2, c2, i2 * g2);
    float h2n = o2 * tanh_f(c2);  // h2[t]

    if (lane < HID) h2g[((size_t)t * NB + b) * HID + lane] = h2n;
    if (lane < 32) {
      h1_lds[j] = h1n;  // lanes 30,31 write ch29 dup into pad slots — never read
      h2_lds[j] = h2n;
    }
    // re-read immediately; latency hides under next iter's xpl read + dot block
#pragma unroll
    for (int p = 0; p < 15; ++p) { h1r[p] = h1p[p]; h2r[p] = h2p[p]; }
  }
}

// ---------------- head MLP: out = relu(h2*lw1^T+lb1)*lw2^T+lb2, zeros for masked t
#define ROWS_PER_BLOCK 32
__global__ void __launch_bounds__(128) final_kernel(
    const float* __restrict__ h2g, const int* __restrict__ lens,
    const float* __restrict__ lw1, const float* __restrict__ lb1,
    const float* __restrict__ lw2, const float* __restrict__ lb2,
    float* __restrict__ out) {
  __shared__ float lw1s[HID][33];
  __shared__ float lw2s[VOCABN][33];
  __shared__ float lb1s[HID];
  __shared__ float lb2s[VOCABN];
  __shared__ float hrow[4][32];
  __shared__ float hmid[4][32];
  int tid = threadIdx.x;
  for (int idx = tid; idx < HID * HID; idx += 128) lw1s[idx / HID][idx % HID] = lw1[idx];
  for (int idx = tid; idx < VOCABN * HID; idx += 128) lw2s[idx / HID][idx % HID] = lw2[idx];
  if (tid < HID) lb1s[tid] = lb1[tid];
  if (tid < VOCABN) lb2s[tid] = lb2[tid];
  __syncthreads();
  int row0 = blockIdx.x * ROWS_PER_BLOCK;
  for (int it = 0; it < ROWS_PER_BLOCK / 4; ++it) {
    int rbase = row0 + it * 4;
    if (tid < 4 * HID) {
      int rid = tid / HID, k = tid % HID;
      int row = rbase + rid;
      int b = row >> 9;        // row / NT
      int t = row & (NT - 1);  // row % NT
      float v = 0.f;
      if (t < lens[b]) v = h2g[(size_t)(t * NB + b) * HID + k];
      hrow[rid][k] = v;
    }
    __syncthreads();
    {
      int rid = tid >> 5, rl = tid & 31;
      if (rl < HID) {
        float m = lb1s[rl];
#pragma unroll
        for (int k = 0; k < HID; ++k) m = fmaf(hrow[rid][k], lw1s[rl][k], m);
        hmid[rid][rl] = fmaxf(m, 0.f);
      }
    }
    __syncthreads();
#pragma unroll
    for (int s = 0; s < 4; ++s) {
      int e = tid + 128 * s;
      if (e < 4 * VOCABN) {
        int rid = e / VOCABN, v = e % VOCABN;
        float o = lb2s[v];
#pragma unroll
        for (int k = 0; k < HID; ++k) o = fmaf(hmid[rid][k], lw2s[v][k], o);
        out[(size_t)(rbase + rid) * VOCABN + v] = o;
      }
    }
    __syncthreads();
  }
}

extern "C" void kernel_launch(void* const* d_in, const int* in_sizes, int n_in,
                              void* d_out, int out_size, void* d_ws, size_t ws_size,
                              hipStream_t stream) {
  const int* batch_x = (const int*)d_in[0];
  const int* lens = (const int*)d_in[1];
  const float* emb = (const float*)d_in[2];
  const float* w_ih1 = (const float*)d_in[3];
  const float* w_hh1 = (const float*)d_in[4];
  const float* b_ih1 = (const float*)d_in[5];
  const float* b_hh1 = (const float*)d_in[6];
  const float* w_ih2 = (const float*)d_in[7];
  const float* w_hh2 = (const float*)d_in[8];
  const float* b_ih2 = (const float*)d_in[9];
  const float* b_hh2 = (const float*)d_in[10];
  const float* lw1 = (const float*)d_in[11];
  const float* lb1 = (const float*)d_in[12];
  const float* lw2 = (const float*)d_in[13];
  const float* lb2 = (const float*)d_in[14];
  float* out = (float*)d_out;

  char* ws = (char*)d_ws;
  float* xpe = (float*)ws;                // 100*120 floats
  float* b2s = (float*)(ws + 48 * 1024);  // 120 floats
  float* h2g = (float*)(ws + 64 * 1024);  // 512*512*30 floats (~31.5 MB)

  prep_kernel<<<VOCABN, 128, 0, stream>>>(emb, w_ih1, b_ih1, b_hh1, b_ih2, b_hh2, xpe, b2s);
  scan_kernel<<<NB, 64, 0, stream>>>(batch_x, lens, xpe, b2s, w_hh1, w_ih2, w_hh2, h2g);
  final_kernel<<<(NB * NT) / ROWS_PER_BLOCK, 128, 0, stream>>>(h2g, lens, lw1, lb1, lw2, lb2, out);
}

// Round 4
// 413.084 us; speedup vs baseline: 1.5943x; 1.1160x over previous
//
#include <hip/hip_runtime.h>
#include <math.h>

#define VOCABN 100
#define EMBEDN 50
#define HID 30
#define NB 512
#define NT 512
#define G4 120  // 4*HID

typedef float v2f __attribute__((ext_vector_type(2)));

__device__ __forceinline__ float tanh_f(float x) { return 1.0f - 2.0f / (1.0f + __expf(2.0f * x)); }
__device__ __forceinline__ v2f mk2(float a, float b) { v2f r; r[0] = a; r[1] = b; return r; }

// ---------------- prep: xpe[tok][g] = emb[tok] @ w_ih1^T + b_ih1 + b_hh1 ; b2s = b_ih2+b_hh2
__global__ void prep_kernel(const float* __restrict__ emb,
                            const float* __restrict__ w_ih1,
                            const float* __restrict__ b_ih1,
                            const float* __restrict__ b_hh1,
                            const float* __restrict__ b_ih2,
                            const float* __restrict__ b_hh2,
                            float* __restrict__ xpe, float* __restrict__ b2s) {
  __shared__ float e[EMBEDN];
  int r = blockIdx.x;
  int tid = threadIdx.x;
  if (tid < EMBEDN) e[tid] = emb[r * EMBEDN + tid];
  __syncthreads();
  if (tid < G4) {
    float s = b_ih1[tid] + b_hh1[tid];
#pragma unroll
    for (int k = 0; k < EMBEDN; ++k) s = fmaf(e[k], w_ih1[tid * EMBEDN + k], s);
    xpe[r * G4 + tid] = s;
    if (r == 0) b2s[tid] = b_ih2[tid] + b_hh2[tid];
  }
}

// ---------------- scan: 3 pipelined waves per sequence.
// W0(t=k): layer1 recurrence (w_hh1).  W1(t=k-1): u = w_ih2 . h1 (stateless).
// W2(t=k-2): layer2 recurrence (w_hh2) + u + nonlin + store.
// One barrier per tick; per-wave weights = 30 v2f = 60 VGPR (no spills, by construction).
__global__ void __launch_bounds__(192) scan_kernel(
    const int* __restrict__ batch_x, const int* __restrict__ lens,
    const float* __restrict__ xpe, const float* __restrict__ b2s,
    const float* __restrict__ w_hh1, const float* __restrict__ w_ih2,
    const float* __restrict__ w_hh2, float* __restrict__ h2g) {
  __shared__ __align__(16) float h1buf[2][32];  // h1[t] at slot t&1
  __shared__ __align__(16) float h2b[32];       // W2-private broadcast
  __shared__ __align__(16) float2 ubuf[2][64];  // u[t] at slot t&1
  __shared__ int tok_lds[NT];

  const int b = blockIdx.x;
  const int tid = threadIdx.x;
  const int wid = tid >> 6;   // 0,1,2
  const int lane = tid & 63;
  const int half = lane >> 5;
  const int j = lane & 31;
  const int jj = (j < HID) ? j : (HID - 1);
  // half0 lane j: gates (i_j, f_j); half1 lane j: gates (g_j, o_j)
  const int gA = half ? (jj + 2 * HID) : jj;
  const int gB = half ? (jj + 3 * HID) : (jj + HID);
  const float bg = half ? 2.0f : 1.0f;  // beta: 1 -> sigmoid, 2 -> tanh

  // stage tokens; zero LDS state
  const int* xrow = batch_x + b * NT;
  for (int i = tid; i < NT; i += 192) tok_lds[i] = xrow[i];
  if (tid < 32) { h1buf[0][tid] = 0.f; h1buf[1][tid] = 0.f; h2b[tid] = 0.f; }
  {
    float2 zz; zz.x = 0.f; zz.y = 0.f;
    if (tid < 128) ((float2*)ubuf)[tid] = zz;
  }

  // per-wave weight slice: 2 rows (gates gA,gB) of one matrix -> 30 v2f
  const float* wsrc = (wid == 0) ? w_hh1 : (wid == 1) ? w_ih2 : w_hh2;
  v2f wA[15], wB[15];
  {
    const float* rA = wsrc + gA * HID;
    const float* rB = wsrc + gB * HID;
#pragma unroll
    for (int p = 0; p < 15; ++p) {
      wA[p] = mk2(rA[2 * p], rA[2 * p + 1]);
      wB[p] = mk2(rB[2 * p], rB[2 * p + 1]);
    }
  }
  const float b2A = b2s[gA], b2B = b2s[gB];
  const int len = lens[b];
  float c = 0.f;  // c1 for W0, c2 for W2
  float xaC = 0.f, xbC = 0.f;
  __syncthreads();
  if (wid == 0) {
    int t0 = tok_lds[0];
    xaC = xpe[t0 * G4 + gA];
    xbC = xpe[t0 * G4 + gB];
  }

  for (int k = 0; k < len + 2; ++k) {
    const int myT = k - wid;
    if (myT >= 0 && myT < len) {
      const float4* hin4 = (wid == 2) ? (const float4*)h2b : (const float4*)h1buf[(k - 1) & 1];
      float4 h4[8];
#pragma unroll
      for (int q = 0; q < 8; ++q) h4[q] = hin4[q];
      v2f aA = mk2(0.f, 0.f), aB = mk2(0.f, 0.f);
#pragma unroll
      for (int p = 0; p < 15; ++p) {
        v2f hp = (p & 1) ? mk2(h4[p >> 1].z, h4[p >> 1].w)
                         : mk2(h4[p >> 1].x, h4[p >> 1].y);
        aA = __builtin_elementwise_fma(hp, wA[p], aA);
        aB = __builtin_elementwise_fma(hp, wB[p], aB);
      }
      float sA_ = aA[0] + aA[1], sB_ = aB[0] + aB[1];
      if (wid == 1) {
        float2 u; u.x = sA_; u.y = sB_;
        ubuf[(k - 1) & 1][lane] = u;  // u[myT] into slot myT&1
      } else {
        float a0, a1;
        if (wid == 0) {
          a0 = sA_ + xaC;
          a1 = sB_ + xbC;
        } else {
          float2 u = ubuf[k & 1][lane];  // u[myT], slot (k-2)&1 == k&1
          a0 = sA_ + u.x + b2A;
          a1 = sB_ + u.y + b2B;
        }
        // branchless nonlinearity: s(x) = 1 - beta/(1+exp(beta*x))
        float sA = 1.0f - bg / (1.0f + __expf(bg * a0));
        float sB = 1.0f - 1.0f / (1.0f + __expf(a1));
        float tA = __shfl_xor(sA, 32, 64);
        float tB = __shfl_xor(sB, 32, 64);
        float i_ = half ? tA : sA, f_ = half ? tB : sB;
        float g_ = half ? sA : tA, o_ = half ? sB : tB;
        c = fmaf(f_, c, i_ * g_);
        float hn = o_ * tanh_f(c);
        if (wid == 0) {
          if (lane < 32) h1buf[k & 1][j] = hn;  // h1[k] -> slot k&1
          int tn = (k + 1 < len) ? tok_lds[k + 1] : 0;  // prefetch x-term, 1 tick slack
          xaC = xpe[tn * G4 + gA];
          xbC = xpe[tn * G4 + gB];
        } else {
          if (lane < 32) h2b[j] = hn;
          if (lane < HID) h2g[((size_t)myT * NB + b) * HID + lane] = hn;
        }
      }
    }
    __syncthreads();
  }
}

// ---------------- head MLP: out = relu(h2*lw1^T+lb1)*lw2^T+lb2, zeros for masked t
#define ROWS_PER_BLOCK 32
__global__ void __launch_bounds__(128) final_kernel(
    const float* __restrict__ h2g, const int* __restrict__ lens,
    const float* __restrict__ lw1, const float* __restrict__ lb1,
    const float* __restrict__ lw2, const float* __restrict__ lb2,
    float* __restrict__ out) {
  __shared__ float lw1s[HID][33];
  __shared__ float lw2s[VOCABN][33];
  __shared__ float lb1s[HID];
  __shared__ float lb2s[VOCABN];
  __shared__ float hrow[4][32];
  __shared__ float hmid[4][32];
  int tid = threadIdx.x;
  for (int idx = tid; idx < HID * HID; idx += 128) lw1s[idx / HID][idx % HID] = lw1[idx];
  for (int idx = tid; idx < VOCABN * HID; idx += 128) lw2s[idx / HID][idx % HID] = lw2[idx];
  if (tid < HID) lb1s[tid] = lb1[tid];
  if (tid < VOCABN) lb2s[tid] = lb2[tid];
  __syncthreads();
  int row0 = blockIdx.x * ROWS_PER_BLOCK;
  for (int it = 0; it < ROWS_PER_BLOCK / 4; ++it) {
    int rbase = row0 + it * 4;
    if (tid < 4 * HID) {
      int rid = tid / HID, k = tid % HID;
      int row = rbase + rid;
      int b = row >> 9;        // row / NT
      int t = row & (NT - 1);  // row % NT
      float v = 0.f;
      if (t < lens[b]) v = h2g[(size_t)(t * NB + b) * HID + k];
      hrow[rid][k] = v;
    }
    __syncthreads();
    {
      int rid = tid >> 5, rl = tid & 31;
      if (rl < HID) {
        float m = lb1s[rl];
#pragma unroll
        for (int k = 0; k < HID; ++k) m = fmaf(hrow[rid][k], lw1s[rl][k], m);
        hmid[rid][rl] = fmaxf(m, 0.f);
      }
    }
    __syncthreads();
#pragma unroll
    for (int s = 0; s < 4; ++s) {
      int e = tid + 128 * s;
      if (e < 4 * VOCABN) {
        int rid = e / VOCABN, v = e % VOCABN;
        float o = lb2s[v];
#pragma unroll
        for (int k = 0; k < HID; ++k) o = fmaf(hmid[rid][k], lw2s[v][k], o);
        out[(size_t)(rbase + rid) * VOCABN + v] = o;
      }
    }
    __syncthreads();
  }
}

extern "C" void kernel_launch(void* const* d_in, const int* in_sizes, int n_in,
                              void* d_out, int out_size, void* d_ws, size_t ws_size,
                              hipStream_t stream) {
  const int* batch_x = (const int*)d_in[0];
  const int* lens = (const int*)d_in[1];
  const float* emb = (const float*)d_in[2];
  const float* w_ih1 = (const float*)d_in[3];
  const float* w_hh1 = (const float*)d_in[4];
  const float* b_ih1 = (const float*)d_in[5];
  const float* b_hh1 = (const float*)d_in[6];
  const float* w_ih2 = (const float*)d_in[7];
  const float* w_hh2 = (const float*)d_in[8];
  const float* b_ih2 = (const float*)d_in[9];
  const float* b_hh2 = (const float*)d_in[10];
  const float* lw1 = (const float*)d_in[11];
  const float* lb1 = (const float*)d_in[12];
  const float* lw2 = (const float*)d_in[13];
  const float* lb2 = (const float*)d_in[14];
  float* out = (float*)d_out;

  char* ws = (char*)d_ws;
  float* xpe = (float*)ws;                // 100*120 floats
  float* b2s = (float*)(ws + 48 * 1024);  // 120 floats
  float* h2g = (float*)(ws + 64 * 1024);  // 512*512*30 floats (~31.5 MB)

  prep_kernel<<<VOCABN, 128, 0, stream>>>(emb, w_ih1, b_ih1, b_hh1, b_ih2, b_hh2, xpe, b2s);
  scan_kernel<<<NB, 192, 0, stream>>>(batch_x, lens, xpe, b2s, w_hh1, w_ih2, w_hh2, h2g);
  final_kernel<<<(NB * NT) / ROWS_PER_BLOCK, 128, 0, stream>>>(h2g, lens, lw1, lb1, lw2, lb2, out);
}